// Round 16
// baseline (124.055 us; speedup 1.0000x reference)
//
#include <hip/hip_runtime.h>

typedef _Float16 h2 __attribute__((ext_vector_type(2)));
typedef _Float16 h4 __attribute__((ext_vector_type(4)));
typedef _Float16 h8 __attribute__((ext_vector_type(8)));
typedef float    f4 __attribute__((ext_vector_type(4)));
typedef float    f16f __attribute__((ext_vector_type(16)));
typedef __fp16   fp16x2 __attribute__((ext_vector_type(2)));
typedef unsigned int u32x4 __attribute__((ext_vector_type(4)));

__device__ __forceinline__ unsigned cvt_pk_u32(float a, float b) {
    fp16x2 t = __builtin_amdgcn_cvt_pkrtz(a, b);
    return __builtin_bit_cast(unsigned, t);
}

// ---------------------------------------------------------------- helpers

__device__ __forceinline__ void gload_lds16(const void* g, void* l) {
    auto gp = reinterpret_cast<const __attribute__((address_space(1))) unsigned int*>(
        reinterpret_cast<uintptr_t>(g));
    auto lp = reinterpret_cast<__attribute__((address_space(3))) unsigned int*>(
        reinterpret_cast<uintptr_t>(l));
    __builtin_amdgcn_global_load_lds(gp, lp, 16, 0, 0);
}

// Stage ROWS x 32-half tile (BK=32, 64B rows = 4x16B units). Swizzle: un ^= (row>>1)&3.
template<int ROWS, int NW>
__device__ __forceinline__ void stage32(const _Float16* __restrict__ gbase, int gstride,
                                        _Float16* lbase)
{
    const int wid = threadIdx.x >> 6, lane = threadIdx.x & 63;
    constexpr int CHUNKS = ROWS / 16;
    #pragma unroll
    for (int c = 0; c < CHUNKS; c += NW) {
        int cc  = c + wid;
        int u   = cc * 64 + lane;
        int row = u >> 2, un = u & 3;
        const _Float16* src = gbase + (size_t)row * gstride + ((un ^ ((row >> 1) & 3)) << 3);
        gload_lds16(src, lbase + cc * 512);
    }
}

// ---------------------------------------------------------------- prep kernels

__global__ void convx_kernel(const float* __restrict__ x, _Float16* __restrict__ xh, int n8)
{
    int i = blockIdx.x * 256 + threadIdx.x;
    if (i >= n8) return;
    const f4* p = (const f4*)(x + (size_t)i * 8);
    f4 a = p[0], b = p[1];
    h8 o;
    #pragma unroll
    for (int j = 0; j < 4; ++j) { o[j] = (_Float16)a[j]; o[j+4] = (_Float16)b[j]; }
    *(h8*)(xh + (size_t)i * 8) = o;
}

// all three weight transposes in one dispatch; grid (64, 16)
__global__ void transw_all_kernel(const float* __restrict__ Wq, const float* __restrict__ Wkv,
                                  const float* __restrict__ Wo,
                                  _Float16* __restrict__ w1t, _Float16* __restrict__ w2t)
{
    __shared__ float tile[64][65];
    int bx = blockIdx.x;
    const float* src; _Float16* dst; int N, n0;
    if (bx < 16)      { src = Wq;  N = 1024; n0 = bx * 64;        dst = w1t; }
    else if (bx < 48) { src = Wkv; N = 2048; n0 = (bx - 16) * 64; dst = w1t + (size_t)1024 * 1024; }
    else              { src = Wo;  N = 1024; n0 = (bx - 48) * 64; dst = w2t; }
    int k0 = blockIdx.y * 64;
    int t = threadIdx.x;
    int tr = t >> 4, tc4 = (t & 15) * 4;
    #pragma unroll
    for (int i = 0; i < 4; ++i) {
        int r = tr + i * 16;
        f4 v = *(const f4*)(src + (size_t)(k0 + r) * N + n0 + tc4);
        tile[r][tc4 + 0] = v[0]; tile[r][tc4 + 1] = v[1];
        tile[r][tc4 + 2] = v[2]; tile[r][tc4 + 3] = v[3];
    }
    __syncthreads();
    #pragma unroll
    for (int i = 0; i < 4; ++i) {
        int r = tr + i * 16;
        h4 ov;
        #pragma unroll
        for (int j = 0; j < 4; ++j) ov[j] = (_Float16)tile[tc4 + j][r];
        *(h4*)(dst + (size_t)(n0 + r) * 1024 + k0 + tc4) = ov;
    }
}

// in-place RoPE on q (cols 0..1023, scaled by 0.125*log2e for base-2 softmax)
// and k (cols 1024..2047); qkv stride 2048. libm sincosf kept deliberately:
// matches the reference's f32 trig rounding.
__global__ void rope_kernel(_Float16* __restrict__ qkv,
                            const int* __restrict__ tq, const int* __restrict__ tk)
{
    int idx = blockIdx.x * 256 + threadIdx.x;
    int row = idx >> 8;
    int c8  = (idx & 255) << 3;
    bool isq = (c8 < 1024);
    int tv = isq ? tq[row] : tk[row];
    _Float16* p = qkv + (size_t)row * 2048 + c8;
    h8 v = *(const h8*)p;
    int p0 = (c8 & 63) >> 1;
    float scale = isq ? 0.125f * 1.4426950408889634f : 1.0f;
    h8 ov;
    #pragma unroll
    for (int j = 0; j < 4; ++j) {
        float invf = exp2f(-(float)(p0 + j) * 0.41524101186092025f);
        float ang  = (float)tv * invf;
        float sv, cv; sincosf(ang, &sv, &cv);
        float x1 = (float)v[2 * j], x2 = (float)v[2 * j + 1];
        ov[2 * j]     = (_Float16)((x1 * cv - x2 * sv) * scale);
        ov[2 * j + 1] = (_Float16)((x1 * sv + x2 * cv) * scale);
    }
    *(h8*)p = ov;
}

// ---------------------------------------------------------------- GEMM1
// BM=256 x BN=128 tile, BK=32, 4 waves each 128x64 out; 3-buffer counted-vmcnt(6).
// vpath: blocks with n0 >= 2048 write V TRANSPOSED to vt[bh][d][n].
__global__ __launch_bounds__(256, 2) void gemm1_kernel(
    const _Float16* __restrict__ A, const _Float16* __restrict__ Bt,
    _Float16* __restrict__ Cout, _Float16* __restrict__ vtout,
    int M, int N, int K, int CN)
{
    __shared__ _Float16 Al[3 * 8192];    // 256 x 32 per buffer
    __shared__ _Float16 Bl[3 * 4096];    // 128 x 32 per buffer
    const int lane = threadIdx.x & 63, wid = threadIdx.x >> 6;
    const int wm = wid >> 1, wn = wid & 1;
    const int m0 = blockIdx.y * 256, n0 = blockIdx.x * 128;
    const int g = lane >> 4, c15 = lane & 15;
    f4 acc[8][4] = {};
    const int nkt = K >> 5;

    stage32<256, 4>(A  + (size_t)m0 * K, K, Al);
    stage32<128, 4>(Bt + (size_t)n0 * K, K, Bl);
    stage32<256, 4>(A  + (size_t)m0 * K + 32, K, Al + 8192);
    stage32<128, 4>(Bt + (size_t)n0 * K + 32, K, Bl + 4096);

    const char* alc = (const char*)Al;
    const char* blc = (const char*)Bl;
    int aoff[8], boff[4];
    #pragma unroll
    for (int i = 0; i < 8; ++i) {
        int ra = wm * 128 + i * 16 + c15;
        aoff[i] = ra * 64 + ((g ^ ((ra >> 1) & 3)) << 4);
    }
    #pragma unroll
    for (int i = 0; i < 4; ++i) {
        int rb = wn * 64 + i * 16 + c15;
        boff[i] = rb * 64 + ((g ^ ((rb >> 1) & 3)) << 4);
    }

    int cur = 0;
    for (int kt = 0; kt < nkt; ++kt) {
        if (kt + 1 < nkt) {
            asm volatile("s_waitcnt vmcnt(6)\n\ts_barrier" ::: "memory");
        } else {
            asm volatile("s_waitcnt vmcnt(0)\n\ts_barrier" ::: "memory");
        }
        if (kt + 2 < nkt) {
            int nxt = cur + 2; if (nxt >= 3) nxt -= 3;
            stage32<256, 4>(A  + (size_t)m0 * K + (kt + 2) * 32, K, Al + nxt * 8192);
            stage32<128, 4>(Bt + (size_t)n0 * K + (kt + 2) * 32, K, Bl + nxt * 4096);
        }
        {
            h8 a[8], b[4];
            #pragma unroll
            for (int mi = 0; mi < 8; ++mi) a[mi] = *(const h8*)(alc + cur * 16384 + aoff[mi]);
            #pragma unroll
            for (int ni = 0; ni < 4; ++ni) b[ni] = *(const h8*)(blc + cur * 8192 + boff[ni]);
            __builtin_amdgcn_s_setprio(1);
            #pragma unroll
            for (int mi = 0; mi < 8; ++mi)
                #pragma unroll
                for (int ni = 0; ni < 4; ++ni)
                    acc[mi][ni] = __builtin_amdgcn_mfma_f32_16x16x32_f16(
                        a[mi], b[ni], acc[mi][ni], 0, 0, 0);
            __builtin_amdgcn_s_setprio(0);
        }
        ++cur; if (cur >= 3) cur = 0;
    }
    const bool vpath = (vtout != nullptr) && (n0 >= 2048);
    #pragma unroll
    for (int mi = 0; mi < 8; ++mi) {
        #pragma unroll
        for (int ni = 0; ni < 4; ++ni) {
            int row0 = m0 + wm * 128 + mi * 16 + g * 4;
            int col  = n0 + wn * 64 + ni * 16 + c15;
            if (vpath) {
                int cv = col - 2048;
                int hh = cv >> 6, dd = cv & 63;
                int bb = row0 >> 11, nn = row0 & 2047;
                h4 ov;
                #pragma unroll
                for (int r = 0; r < 4; ++r) ov[r] = (_Float16)acc[mi][ni][r];
                *(h4*)(vtout + (size_t)((bb * 16 + hh) * 64 + dd) * 2048 + nn) = ov;
            } else {
                #pragma unroll
                for (int r = 0; r < 4; ++r)
                    Cout[(size_t)(row0 + r) * CN + col] = (_Float16)acc[mi][ni][r];
            }
        }
    }
}

// ---------------------------------------------------------------- GEMM2
// 128x128 tile, BK=32, 4 waves each 64x64; 3-buffer counted-vmcnt(4); f32 out + bias.
__global__ __launch_bounds__(256) void gemm2_kernel(
    const _Float16* __restrict__ A, const _Float16* __restrict__ Bt,
    float* __restrict__ Cout, const float* __restrict__ bias,
    int M, int N, int K, int CN)
{
    __shared__ _Float16 Al[3 * 4096];
    __shared__ _Float16 Bl[3 * 4096];
    const int lane = threadIdx.x & 63, wid = threadIdx.x >> 6;
    const int wm = wid >> 1, wn = wid & 1;
    const int m0 = blockIdx.y * 128, n0 = blockIdx.x * 128;
    const int g = lane >> 4, c15 = lane & 15;
    f4 acc[4][4] = {};
    const int nkt = K >> 5;

    stage32<128, 4>(A  + (size_t)m0 * K, K, Al);
    stage32<128, 4>(Bt + (size_t)n0 * K, K, Bl);
    stage32<128, 4>(A  + (size_t)m0 * K + 32, K, Al + 4096);
    stage32<128, 4>(Bt + (size_t)n0 * K + 32, K, Bl + 4096);

    const char* alc = (const char*)Al;
    const char* blc = (const char*)Bl;
    int aoff[4], boff[4];
    #pragma unroll
    for (int i = 0; i < 4; ++i) {
        int ra = wm * 64 + i * 16 + c15;
        int rb = wn * 64 + i * 16 + c15;
        aoff[i] = ra * 64 + ((g ^ ((ra >> 1) & 3)) << 4);
        boff[i] = rb * 64 + ((g ^ ((rb >> 1) & 3)) << 4);
    }

    int cur = 0;
    for (int kt = 0; kt < nkt; ++kt) {
        if (kt + 1 < nkt) {
            asm volatile("s_waitcnt vmcnt(4)\n\ts_barrier" ::: "memory");
        } else {
            asm volatile("s_waitcnt vmcnt(0)\n\ts_barrier" ::: "memory");
        }
        if (kt + 2 < nkt) {
            int nxt = cur + 2; if (nxt >= 3) nxt -= 3;
            stage32<128, 4>(A  + (size_t)m0 * K + (kt + 2) * 32, K, Al + nxt * 4096);
            stage32<128, 4>(Bt + (size_t)n0 * K + (kt + 2) * 32, K, Bl + nxt * 4096);
        }
        {
            h8 a[4], b[4];
            #pragma unroll
            for (int mi = 0; mi < 4; ++mi) a[mi] = *(const h8*)(alc + cur * 8192 + aoff[mi]);
            #pragma unroll
            for (int ni = 0; ni < 4; ++ni) b[ni] = *(const h8*)(blc + cur * 8192 + boff[ni]);
            __builtin_amdgcn_s_setprio(1);
            #pragma unroll
            for (int mi = 0; mi < 4; ++mi)
                #pragma unroll
                for (int ni = 0; ni < 4; ++ni)
                    acc[mi][ni] = __builtin_amdgcn_mfma_f32_16x16x32_f16(
                        a[mi], b[ni], acc[mi][ni], 0, 0, 0);
            __builtin_amdgcn_s_setprio(0);
        }
        ++cur; if (cur >= 3) cur = 0;
    }
    #pragma unroll
    for (int mi = 0; mi < 4; ++mi) {
        #pragma unroll
        for (int ni = 0; ni < 4; ++ni) {
            int row0 = m0 + wm * 64 + mi * 16 + g * 4;
            int col  = n0 + wn * 64 + ni * 16 + c15;
            float bv = bias[col];
            #pragma unroll
            for (int r = 0; r < 4; ++r)
                Cout[(size_t)(row0 + r) * CN + col] = acc[mi][ni][r] + bv;
        }
    }
}

// ---------------------------------------------------------------- flash attention
// grid 512 flat blocks, XCD-swizzled; 4 waves, each 32 q-rows; KVBLK=128
// (two 64-kv subtiles per tile, stored [K0|K1|V0|V1] in the per-64 layout).
// 2 buffers x 32KB; ONE {vmcnt(0); s_barrier} per 128 kv (T3-min: stage(t+1)
// issued before compute(t), drain lands after a full compute phase).
// Fixed-m softmax P = exp2(s) (exact; bias cancels in normalization).
__global__ __launch_bounds__(256, 2) void attn_kernel(
    const _Float16* __restrict__ qkv, const _Float16* __restrict__ vt,
    _Float16* __restrict__ ao)
{
    __shared__ _Float16 smem[32768];                   // 2 bufs x 16384 halfs
    const int lane = threadIdx.x & 63, wid = threadIdx.x >> 6;
    const int q32 = lane & 31, h = lane >> 5;
    const int i = blockIdx.x;
    const int qt = (i >> 3) & 15;
    const int bh = (i & 7) + 8 * (i >> 7);
    const int b = bh >> 4, hh = bh & 15;
    const int q0 = qt * 128;

    const _Float16* Kg = qkv + (size_t)(b * 2048) * 2048 + 1024 + hh * 64;
    const _Float16* Vg = vt + (size_t)bh * 64 * 2048;

    const int srow = wid * 8 + (lane >> 3);
    const int sswz = ((lane & 7) ^ (srow & 7)) << 3;
    const _Float16* kst = Kg + (size_t)srow * 2048 + sswz;   // K rows = kv
    const _Float16* vst = Vg + (size_t)srow * 2048 + sswz;   // V rows = d, cols walk kv

    // buffer layout (halfs): K0 [0,4096) | K1 [4096,8192) | V0 [8192,12288) | V1 [12288,16384)
#define STAGE(BUF)                                                                   \
    {                                                                                \
        gload_lds16(kst,                      smem + (BUF) * 16384 + wid * 512);     \
        gload_lds16(kst + (size_t)32 * 2048,  smem + (BUF) * 16384 + (wid + 4) * 512); \
        gload_lds16(kst + (size_t)64 * 2048,  smem + (BUF) * 16384 + 4096 + wid * 512); \
        gload_lds16(kst + (size_t)96 * 2048,  smem + (BUF) * 16384 + 4096 + (wid + 4) * 512); \
        gload_lds16(vst,                      smem + (BUF) * 16384 + 8192 + wid * 512); \
        gload_lds16(vst + (size_t)32 * 2048,  smem + (BUF) * 16384 + 8192 + (wid + 4) * 512); \
        gload_lds16(vst + 64,                 smem + (BUF) * 16384 + 12288 + wid * 512); \
        gload_lds16(vst + (size_t)32 * 2048 + 64, smem + (BUF) * 16384 + 12288 + (wid + 4) * 512); \
        kst += (size_t)128 * 2048; vst += 128;                                       \
    }

    STAGE(0)

    const int qrow = q0 + wid * 32 + q32;
    const _Float16* Qg = qkv + (size_t)(b * 2048 + qrow) * 2048 + hh * 64 + h * 8;
    h8 qf[4];
    #pragma unroll
    for (int ds = 0; ds < 4; ++ds) qf[ds] = *(const h8*)(Qg + ds * 16);

    const char* sbc = (const char*)smem;
    const int r7 = q32 & 7;
    int bkb[4], bvb[4];
    #pragma unroll
    for (int ii = 0; ii < 4; ++ii) {
        int swz = (((ii * 2 + h) ^ r7) << 4);
        bkb[ii] = q32 * 128 + swz;              // + CUR*32768 + HALF*8192
        bvb[ii] = 16384 + q32 * 128 + swz;      // + CUR*32768 + HALF*8192
    }

    f16f o0 = {}, o1 = {};
    f4 dacc4 = {};

#define MAKE_PA(SV, PA_A, PA_B)                                                      \
    {                                                                                \
        float e[16];                                                                 \
        _Pragma("unroll")                                                            \
        for (int r = 0; r < 16; ++r) { e[r] = __builtin_amdgcn_exp2f(SV[r]);         \
                                       dacc4[r & 3] += e[r]; }                       \
        unsigned wA = cvt_pk_u32(e[0], e[1]), wB = cvt_pk_u32(e[2], e[3]);           \
        unsigned wC = cvt_pk_u32(e[4], e[5]), wD = cvt_pk_u32(e[6], e[7]);           \
        asm volatile("v_permlane32_swap_b32 %0, %1" : "+v"(wA), "+v"(wC));           \
        asm volatile("v_permlane32_swap_b32 %0, %1" : "+v"(wB), "+v"(wD));           \
        u32x4 ta = {wA, wB, wC, wD};                                                 \
        PA_A = __builtin_bit_cast(h8, ta);                                           \
        unsigned xA = cvt_pk_u32(e[8], e[9]),  xB = cvt_pk_u32(e[10], e[11]);        \
        unsigned xC = cvt_pk_u32(e[12], e[13]), xD = cvt_pk_u32(e[14], e[15]);       \
        asm volatile("v_permlane32_swap_b32 %0, %1" : "+v"(xA), "+v"(xC));           \
        asm volatile("v_permlane32_swap_b32 %0, %1" : "+v"(xB), "+v"(xD));           \
        u32x4 tb = {xA, xB, xC, xD};                                                 \
        PA_B = __builtin_bit_cast(h8, tb);                                           \
    }

#define COMPUTE_H(CUR, HALF)                                                         \
    {                                                                                \
        const int kb = (CUR) * 32768 + (HALF) * 8192;                                \
        const int vb = (CUR) * 32768 + (HALF) * 8192;                                \
        f16f s0 = {}, s1 = {};                                                       \
        __builtin_amdgcn_s_setprio(1);                                               \
        _Pragma("unroll")                                                            \
        for (int ds = 0; ds < 4; ++ds) {                                             \
            h8 klo = *(const h8*)(sbc + bkb[ds] + kb);                               \
            h8 khi = *(const h8*)(sbc + bkb[ds] + kb + 4096);                        \
            s0 = __builtin_amdgcn_mfma_f32_32x32x16_f16(klo, qf[ds], s0, 0, 0, 0);   \
            s1 = __builtin_amdgcn_mfma_f32_32x32x16_f16(khi, qf[ds], s1, 0, 0, 0);   \
        }                                                                            \
        __builtin_amdgcn_s_setprio(0);                                               \
        h8 pa0, pa1, pa2, pa3;                                                       \
        MAKE_PA(s0, pa0, pa1)                                                        \
        MAKE_PA(s1, pa2, pa3)                                                        \
        __builtin_amdgcn_s_setprio(1);                                               \
        _Pragma("unroll")                                                            \
        for (int ks = 0; ks < 4; ++ks) {                                             \
            h8 pb = (ks == 0) ? pa0 : (ks == 1) ? pa1 : (ks == 2) ? pa2 : pa3;       \
            h8 vlo = *(const h8*)(sbc + bvb[ks] + vb);                               \
            h8 vhi = *(const h8*)(sbc + bvb[ks] + vb + 4096);                        \
            o0 = __builtin_amdgcn_mfma_f32_32x32x16_f16(vlo, pb, o0, 0, 0, 0);       \
            o1 = __builtin_amdgcn_mfma_f32_32x32x16_f16(vhi, pb, o1, 0, 0, 0);       \
        }                                                                            \
        __builtin_amdgcn_s_setprio(0);                                               \
    }

#define SYNC0 asm volatile("s_waitcnt vmcnt(0)\n\ts_barrier" ::: "memory");

    // 16 tiles of 128 kv; one barrier per tile
    for (int t = 0; t < 15; ++t) {
        SYNC0
        STAGE((t + 1) & 1)
        COMPUTE_H(t & 1, 0)
        COMPUTE_H(t & 1, 1)
    }
    SYNC0
    COMPUTE_H(1, 0)
    COMPUTE_H(1, 1)

#undef SYNC0
#undef COMPUTE_H
#undef MAKE_PA
#undef STAGE

    float l_loc = (dacc4[0] + dacc4[1]) + (dacc4[2] + dacc4[3]);
    float l_tot = l_loc + __shfl_xor(l_loc, 32);
    float inv_l = 1.f / l_tot;
    const int token = b * 2048 + qrow;
    _Float16* aop = ao + (size_t)token * 1024 + hh * 64 + 4 * h;
    #pragma unroll
    for (int w = 0; w < 4; ++w) {
        h4 ov;
        #pragma unroll
        for (int r = 0; r < 4; ++r) ov[r] = (_Float16)(o0[w * 4 + r] * inv_l);
        *(h4*)(aop + w * 8) = ov;
    }
    #pragma unroll
    for (int w = 0; w < 4; ++w) {
        h4 ov;
        #pragma unroll
        for (int r = 0; r < 4; ++r) ov[r] = (_Float16)(o1[w * 4 + r] * inv_l);
        *(h4*)(aop + 32 + w * 8) = ov;
    }
}

// ---------------------------------------------------------------- launch

extern "C" void kernel_launch(void* const* d_in, const int* in_sizes, int n_in,
                              void* d_out, int out_size, void* d_ws, size_t ws_size,
                              hipStream_t stream) {
    const float* x   = (const float*)d_in[0];
    const int*   tq  = (const int*)d_in[1];
    const int*   tk  = (const int*)d_in[2];
    const float* Wq  = (const float*)d_in[3];
    const float* Wkv = (const float*)d_in[4];
    const float* Wo  = (const float*)d_in[5];
    const float* bo  = (const float*)d_in[6];
    float* out = (float*)d_out;

    char* ws = (char*)d_ws;
    _Float16* xh  = (_Float16*)(ws);                    //  8 MB [4096][1024]
    _Float16* w1t = (_Float16*)(ws + 8388608);          //  6 MB [3072][1024]
    _Float16* w2t = (_Float16*)(ws + 14680064);         //  2 MB [1024][1024]
    _Float16* qkv = (_Float16*)(ws + 16777216);         // 16 MB [4096][2048] (q|k)
    _Float16* vt  = (_Float16*)(ws + 33554432);         //  8 MB [32 bh][64 d][2048 n]
    _Float16* ao  = (_Float16*)(ws + 41943040);         //  8 MB [4096][1024]

    convx_kernel<<<2048, 256, 0, stream>>>(x, xh, 524288);
    transw_all_kernel<<<dim3(64, 16), 256, 0, stream>>>(Wq, Wkv, Wo, w1t, w2t);

    gemm1_kernel<<<dim3(24, 16), 256, 0, stream>>>(xh, w1t, qkv, vt,
                                                   4096, 3072, 1024, 2048);

    rope_kernel<<<4096, 256, 0, stream>>>(qkv, tq, tk);

    attn_kernel<<<512, 256, 0, stream>>>(qkv, vt, ao);

    gemm2_kernel<<<dim3(8, 32), 256, 0, stream>>>(ao, w2t, out, bo,
                                                  4096, 1024, 1024, 1024);
}

// Round 17
// 121.158 us; speedup vs baseline: 1.0239x; 1.0239x over previous
//
#include <hip/hip_runtime.h>

typedef _Float16 h2 __attribute__((ext_vector_type(2)));
typedef _Float16 h4 __attribute__((ext_vector_type(4)));
typedef _Float16 h8 __attribute__((ext_vector_type(8)));
typedef float    f4 __attribute__((ext_vector_type(4)));
typedef float    f16f __attribute__((ext_vector_type(16)));
typedef __fp16   fp16x2 __attribute__((ext_vector_type(2)));
typedef unsigned int u32x4 __attribute__((ext_vector_type(4)));

__device__ __forceinline__ unsigned cvt_pk_u32(float a, float b) {
    fp16x2 t = __builtin_amdgcn_cvt_pkrtz(a, b);
    return __builtin_bit_cast(unsigned, t);
}

// ---------------------------------------------------------------- helpers

__device__ __forceinline__ void gload_lds16(const void* g, void* l) {
    auto gp = reinterpret_cast<const __attribute__((address_space(1))) unsigned int*>(
        reinterpret_cast<uintptr_t>(g));
    auto lp = reinterpret_cast<__attribute__((address_space(3))) unsigned int*>(
        reinterpret_cast<uintptr_t>(l));
    __builtin_amdgcn_global_load_lds(gp, lp, 16, 0, 0);
}

// Stage ROWS x 32-half tile (BK=32, 64B rows = 4x16B units). Swizzle: un ^= (row>>1)&3.
template<int ROWS, int NW>
__device__ __forceinline__ void stage32(const _Float16* __restrict__ gbase, int gstride,
                                        _Float16* lbase)
{
    const int wid = threadIdx.x >> 6, lane = threadIdx.x & 63;
    constexpr int CHUNKS = ROWS / 16;
    #pragma unroll
    for (int c = 0; c < CHUNKS; c += NW) {
        int cc  = c + wid;
        int u   = cc * 64 + lane;
        int row = u >> 2, un = u & 3;
        const _Float16* src = gbase + (size_t)row * gstride + ((un ^ ((row >> 1) & 3)) << 3);
        gload_lds16(src, lbase + cc * 512);
    }
}

// ---------------------------------------------------------------- prep kernels

__global__ void convx_kernel(const float* __restrict__ x, _Float16* __restrict__ xh, int n8)
{
    int i = blockIdx.x * 256 + threadIdx.x;
    if (i >= n8) return;
    const f4* p = (const f4*)(x + (size_t)i * 8);
    f4 a = p[0], b = p[1];
    h8 o;
    #pragma unroll
    for (int j = 0; j < 4; ++j) { o[j] = (_Float16)a[j]; o[j+4] = (_Float16)b[j]; }
    *(h8*)(xh + (size_t)i * 8) = o;
}

// all three weight transposes in one dispatch; grid (64, 16)
__global__ void transw_all_kernel(const float* __restrict__ Wq, const float* __restrict__ Wkv,
                                  const float* __restrict__ Wo,
                                  _Float16* __restrict__ w1t, _Float16* __restrict__ w2t)
{
    __shared__ float tile[64][65];
    int bx = blockIdx.x;
    const float* src; _Float16* dst; int N, n0;
    if (bx < 16)      { src = Wq;  N = 1024; n0 = bx * 64;        dst = w1t; }
    else if (bx < 48) { src = Wkv; N = 2048; n0 = (bx - 16) * 64; dst = w1t + (size_t)1024 * 1024; }
    else              { src = Wo;  N = 1024; n0 = (bx - 48) * 64; dst = w2t; }
    int k0 = blockIdx.y * 64;
    int t = threadIdx.x;
    int tr = t >> 4, tc4 = (t & 15) * 4;
    #pragma unroll
    for (int i = 0; i < 4; ++i) {
        int r = tr + i * 16;
        f4 v = *(const f4*)(src + (size_t)(k0 + r) * N + n0 + tc4);
        tile[r][tc4 + 0] = v[0]; tile[r][tc4 + 1] = v[1];
        tile[r][tc4 + 2] = v[2]; tile[r][tc4 + 3] = v[3];
    }
    __syncthreads();
    #pragma unroll
    for (int i = 0; i < 4; ++i) {
        int r = tr + i * 16;
        h4 ov;
        #pragma unroll
        for (int j = 0; j < 4; ++j) ov[j] = (_Float16)tile[tc4 + j][r];
        *(h4*)(dst + (size_t)(n0 + r) * 1024 + k0 + tc4) = ov;
    }
}

// in-place RoPE on q (cols 0..1023, scaled by 0.125*log2e for base-2 softmax)
// and k (cols 1024..2047); qkv stride 2048. libm sincosf kept deliberately:
// matches the reference's f32 trig rounding.
__global__ void rope_kernel(_Float16* __restrict__ qkv,
                            const int* __restrict__ tq, const int* __restrict__ tk)
{
    int idx = blockIdx.x * 256 + threadIdx.x;
    int row = idx >> 8;
    int c8  = (idx & 255) << 3;
    bool isq = (c8 < 1024);
    int tv = isq ? tq[row] : tk[row];
    _Float16* p = qkv + (size_t)row * 2048 + c8;
    h8 v = *(const h8*)p;
    int p0 = (c8 & 63) >> 1;
    float scale = isq ? 0.125f * 1.4426950408889634f : 1.0f;
    h8 ov;
    #pragma unroll
    for (int j = 0; j < 4; ++j) {
        float invf = exp2f(-(float)(p0 + j) * 0.41524101186092025f);
        float ang  = (float)tv * invf;
        float sv, cv; sincosf(ang, &sv, &cv);
        float x1 = (float)v[2 * j], x2 = (float)v[2 * j + 1];
        ov[2 * j]     = (_Float16)((x1 * cv - x2 * sv) * scale);
        ov[2 * j + 1] = (_Float16)((x1 * sv + x2 * cv) * scale);
    }
    *(h8*)p = ov;
}

// ---------------------------------------------------------------- GEMM
// C[M,N] = A[M,K] @ Bt[N,K]^T ; 128x128 tile, BK=32, 4 waves each 64x64.
// 3-buffer counted-vmcnt pipeline. CN = C row stride. vpath: n0 >= 2048
// blocks write V TRANSPOSED to vt[bh][d][n].
template<bool OUT32>
__global__ __launch_bounds__(256) void gemm_kernel(
    const _Float16* __restrict__ A, const _Float16* __restrict__ Bt,
    void* __restrict__ Cout, const float* __restrict__ bias,
    _Float16* __restrict__ vtout,
    int M, int N, int K, int CN)
{
    __shared__ _Float16 Al[3 * 4096];
    __shared__ _Float16 Bl[3 * 4096];
    const int lane = threadIdx.x & 63, wid = threadIdx.x >> 6;
    const int wm = wid >> 1, wn = wid & 1;
    const int m0 = blockIdx.y * 128, n0 = blockIdx.x * 128;
    const int g = lane >> 4, c15 = lane & 15;
    f4 acc[4][4] = {};
    const int nkt = K >> 5;

    stage32<128, 4>(A  + (size_t)m0 * K, K, Al);
    stage32<128, 4>(Bt + (size_t)n0 * K, K, Bl);
    stage32<128, 4>(A  + (size_t)m0 * K + 32, K, Al + 4096);
    stage32<128, 4>(Bt + (size_t)n0 * K + 32, K, Bl + 4096);

    const char* alc = (const char*)Al;
    const char* blc = (const char*)Bl;
    int aoff[4], boff[4];
    #pragma unroll
    for (int i = 0; i < 4; ++i) {
        int ra = wm * 64 + i * 16 + c15;
        int rb = wn * 64 + i * 16 + c15;
        aoff[i] = ra * 64 + ((g ^ ((ra >> 1) & 3)) << 4);
        boff[i] = rb * 64 + ((g ^ ((rb >> 1) & 3)) << 4);
    }

    int cur = 0;
    for (int kt = 0; kt < nkt; ++kt) {
        if (kt + 1 < nkt) {
            asm volatile("s_waitcnt vmcnt(4)\n\ts_barrier" ::: "memory");
        } else {
            asm volatile("s_waitcnt vmcnt(0)\n\ts_barrier" ::: "memory");
        }
        if (kt + 2 < nkt) {
            int nxt = cur + 2; if (nxt >= 3) nxt -= 3;
            stage32<128, 4>(A  + (size_t)m0 * K + (kt + 2) * 32, K, Al + nxt * 4096);
            stage32<128, 4>(Bt + (size_t)n0 * K + (kt + 2) * 32, K, Bl + nxt * 4096);
        }
        {
            h8 a[4], b[4];
            #pragma unroll
            for (int mi = 0; mi < 4; ++mi) a[mi] = *(const h8*)(alc + cur * 8192 + aoff[mi]);
            #pragma unroll
            for (int ni = 0; ni < 4; ++ni) b[ni] = *(const h8*)(blc + cur * 8192 + boff[ni]);
            __builtin_amdgcn_s_setprio(1);
            #pragma unroll
            for (int mi = 0; mi < 4; ++mi)
                #pragma unroll
                for (int ni = 0; ni < 4; ++ni)
                    acc[mi][ni] = __builtin_amdgcn_mfma_f32_16x16x32_f16(
                        a[mi], b[ni], acc[mi][ni], 0, 0, 0);
            __builtin_amdgcn_s_setprio(0);
        }
        ++cur; if (cur >= 3) cur = 0;
    }
    const bool vpath = (!OUT32) && (vtout != nullptr) && (n0 >= 2048);
    #pragma unroll
    for (int mi = 0; mi < 4; ++mi) {
        #pragma unroll
        for (int ni = 0; ni < 4; ++ni) {
            int row0 = m0 + wm * 64 + mi * 16 + g * 4;
            int col  = n0 + wn * 64 + ni * 16 + c15;
            if (OUT32) {
                float bv = bias ? bias[col] : 0.f;
                float* C = (float*)Cout;
                #pragma unroll
                for (int r = 0; r < 4; ++r)
                    C[(size_t)(row0 + r) * CN + col] = acc[mi][ni][r] + bv;
            } else if (vpath) {
                int cv = col - 2048;
                int hh = cv >> 6, dd = cv & 63;
                int bb = row0 >> 11, nn = row0 & 2047;
                h4 ov;
                #pragma unroll
                for (int r = 0; r < 4; ++r) ov[r] = (_Float16)acc[mi][ni][r];
                *(h4*)(vtout + (size_t)((bb * 16 + hh) * 64 + dd) * 2048 + nn) = ov;
            } else {
                _Float16* C = (_Float16*)Cout;
                #pragma unroll
                for (int r = 0; r < 4; ++r)
                    C[(size_t)(row0 + r) * CN + col] = (_Float16)acc[mi][ni][r];
            }
        }
    }
}

// ---------------------------------------------------------------- flash attention
// grid 512 flat blocks, XCD-swizzled; 4 waves, each 32 q-rows; KVBLK=64;
// 3-buffer LDS pipeline, counted vmcnt. T15 cross-tile software pipeline:
// QK(t+1) is computed BEFORE SM/PV(t) in program order, so the scheduler
// interleaves QK's MFMA chains with softmax VALU (chains hidden both ways).
// Fixed-m softmax P = exp2(s) (exact; bias cancels in normalization).
__global__ __launch_bounds__(256, 2) void attn_kernel(
    const _Float16* __restrict__ qkv, const _Float16* __restrict__ vt,
    _Float16* __restrict__ ao)
{
    __shared__ _Float16 smem[24576];                   // 3 bufs x [K 64x64 | V 64x64]
    const int lane = threadIdx.x & 63, wid = threadIdx.x >> 6;
    const int q32 = lane & 31, h = lane >> 5;
    const int i = blockIdx.x;
    const int qt = (i >> 3) & 15;
    const int bh = (i & 7) + 8 * (i >> 7);
    const int b = bh >> 4, hh = bh & 15;
    const int q0 = qt * 128;

    const _Float16* Kg = qkv + (size_t)(b * 2048) * 2048 + 1024 + hh * 64;
    const _Float16* Vg = vt + (size_t)bh * 64 * 2048;

    const int srow = wid * 8 + (lane >> 3);
    const int sswz = ((lane & 7) ^ (srow & 7)) << 3;
    const _Float16* kst  = Kg + (size_t)srow * 2048 + sswz;
    const _Float16* kst2 = kst + (size_t)32 * 2048;
    const _Float16* vst  = Vg + (size_t)srow * 2048 + sswz;
    const _Float16* vst2 = vst + (size_t)32 * 2048;

#define STAGE(BUF)                                                                   \
    {                                                                                \
        gload_lds16(kst,  smem + (BUF) * 8192 + wid * 512);                          \
        gload_lds16(kst2, smem + (BUF) * 8192 + (wid + 4) * 512);                    \
        gload_lds16(vst,  smem + (BUF) * 8192 + 4096 + wid * 512);                   \
        gload_lds16(vst2, smem + (BUF) * 8192 + 4096 + (wid + 4) * 512);             \
        kst += 64 * 2048; kst2 += 64 * 2048; vst += 64; vst2 += 64;                  \
    }

    STAGE(0) STAGE(1)

    const int qrow = q0 + wid * 32 + q32;
    const _Float16* Qg = qkv + (size_t)(b * 2048 + qrow) * 2048 + hh * 64 + h * 8;
    h8 qf[4];
    #pragma unroll
    for (int ds = 0; ds < 4; ++ds) qf[ds] = *(const h8*)(Qg + ds * 16);

    const char* sbc = (const char*)smem;
    const int r7 = q32 & 7;
    int bk[4], bv[4];
    #pragma unroll
    for (int ii = 0; ii < 4; ++ii) {
        int swz = (((ii * 2 + h) ^ r7) << 4);
        bk[ii] = q32 * 128 + swz;
        bv[ii] = 8192 + q32 * 128 + swz;
    }

    f16f o0 = {}, o1 = {};
    f4 dacc4 = {};
    f16f sA0, sA1, sB0, sB1;

#define QKM(CUR, S0, S1)                                                             \
    {                                                                                \
        S0 = (f16f){}; S1 = (f16f){};                                                \
        __builtin_amdgcn_s_setprio(1);                                               \
        _Pragma("unroll")                                                            \
        for (int ds = 0; ds < 4; ++ds) {                                             \
            h8 klo = *(const h8*)(sbc + bk[ds] + (CUR) * 16384);                     \
            h8 khi = *(const h8*)(sbc + bk[ds] + (CUR) * 16384 + 4096);              \
            S0 = __builtin_amdgcn_mfma_f32_32x32x16_f16(klo, qf[ds], S0, 0, 0, 0);   \
            S1 = __builtin_amdgcn_mfma_f32_32x32x16_f16(khi, qf[ds], S1, 0, 0, 0);   \
        }                                                                            \
        __builtin_amdgcn_s_setprio(0);                                               \
    }

#define MAKE_PA(SV, PA_A, PA_B)                                                      \
    {                                                                                \
        float e[16];                                                                 \
        _Pragma("unroll")                                                            \
        for (int r = 0; r < 16; ++r) { e[r] = __builtin_amdgcn_exp2f(SV[r]);         \
                                       dacc4[r & 3] += e[r]; }                       \
        unsigned wA = cvt_pk_u32(e[0], e[1]), wB = cvt_pk_u32(e[2], e[3]);           \
        unsigned wC = cvt_pk_u32(e[4], e[5]), wD = cvt_pk_u32(e[6], e[7]);           \
        asm volatile("v_permlane32_swap_b32 %0, %1" : "+v"(wA), "+v"(wC));           \
        asm volatile("v_permlane32_swap_b32 %0, %1" : "+v"(wB), "+v"(wD));           \
        u32x4 ta = {wA, wB, wC, wD};                                                 \
        PA_A = __builtin_bit_cast(h8, ta);                                           \
        unsigned xA = cvt_pk_u32(e[8], e[9]),  xB = cvt_pk_u32(e[10], e[11]);        \
        unsigned xC = cvt_pk_u32(e[12], e[13]), xD = cvt_pk_u32(e[14], e[15]);       \
        asm volatile("v_permlane32_swap_b32 %0, %1" : "+v"(xA), "+v"(xC));           \
        asm volatile("v_permlane32_swap_b32 %0, %1" : "+v"(xB), "+v"(xD));           \
        u32x4 tb = {xA, xB, xC, xD};                                                 \
        PA_B = __builtin_bit_cast(h8, tb);                                           \
    }

#define SMPV(S0, S1, CUR)                                                            \
    {                                                                                \
        h8 pa0, pa1, pa2, pa3;                                                       \
        MAKE_PA(S0, pa0, pa1)                                                        \
        MAKE_PA(S1, pa2, pa3)                                                        \
        __builtin_amdgcn_s_setprio(1);                                               \
        _Pragma("unroll")                                                            \
        for (int ks = 0; ks < 4; ++ks) {                                             \
            h8 pb = (ks == 0) ? pa0 : (ks == 1) ? pa1 : (ks == 2) ? pa2 : pa3;       \
            h8 vlo = *(const h8*)(sbc + bv[ks] + (CUR) * 16384);                     \
            h8 vhi = *(const h8*)(sbc + bv[ks] + (CUR) * 16384 + 4096);              \
            o0 = __builtin_amdgcn_mfma_f32_32x32x16_f16(vlo, pb, o0, 0, 0, 0);       \
            o1 = __builtin_amdgcn_mfma_f32_32x32x16_f16(vhi, pb, o1, 0, 0, 0);       \
        }                                                                            \
        __builtin_amdgcn_s_setprio(0);                                               \
    }

#define SYNC0 asm volatile("s_waitcnt vmcnt(0)\n\ts_barrier" ::: "memory");
#define SYNC4 asm volatile("s_waitcnt vmcnt(4)\n\ts_barrier" ::: "memory");

    SYNC4                       // buf0 landed (buf1's 4 loads still in flight)
    QKM(0, sA0, sA1)

    // iters t = 6k..6k+5, k = 0..4 (t = 0..29):
    //   SYNC0; STAGE((t+2)%3); QK(t+1 -> other set); SMPV(current set, buf t%3)
    for (int k = 0; k < 5; ++k) {
        SYNC0 STAGE(2) QKM(1, sB0, sB1) SMPV(sA0, sA1, 0)
        SYNC0 STAGE(0) QKM(2, sA0, sA1) SMPV(sB0, sB1, 1)
        SYNC0 STAGE(1) QKM(0, sB0, sB1) SMPV(sA0, sA1, 2)
        SYNC0 STAGE(2) QKM(1, sA0, sA1) SMPV(sB0, sB1, 0)
        SYNC0 STAGE(0) QKM(2, sB0, sB1) SMPV(sA0, sA1, 1)
        SYNC0 STAGE(1) QKM(0, sA0, sA1) SMPV(sB0, sB1, 2)
    }
    // t = 30: buf1 (tile 31) already staged at t=29; drain it, no more staging
    SYNC0 QKM(1, sB0, sB1) SMPV(sA0, sA1, 0)
    // t = 31
    SMPV(sB0, sB1, 1)

#undef SYNC0
#undef SYNC4
#undef SMPV
#undef MAKE_PA
#undef QKM
#undef STAGE

    float l_loc = (dacc4[0] + dacc4[1]) + (dacc4[2] + dacc4[3]);
    float l_tot = l_loc + __shfl_xor(l_loc, 32);
    float inv_l = 1.f / l_tot;
    const int token = b * 2048 + qrow;
    _Float16* aop = ao + (size_t)token * 1024 + hh * 64 + 4 * h;
    #pragma unroll
    for (int w = 0; w < 4; ++w) {
        h4 ov;
        #pragma unroll
        for (int r = 0; r < 4; ++r) ov[r] = (_Float16)(o0[w * 4 + r] * inv_l);
        *(h4*)(aop + w * 8) = ov;
    }
    #pragma unroll
    for (int w = 0; w < 4; ++w) {
        h4 ov;
        #pragma unroll
        for (int r = 0; r < 4; ++r) ov[r] = (_Float16)(o1[w * 4 + r] * inv_l);
        *(h4*)(aop + 32 + w * 8) = ov;
    }
}

// ---------------------------------------------------------------- launch

extern "C" void kernel_launch(void* const* d_in, const int* in_sizes, int n_in,
                              void* d_out, int out_size, void* d_ws, size_t ws_size,
                              hipStream_t stream) {
    const float* x   = (const float*)d_in[0];
    const int*   tq  = (const int*)d_in[1];
    const int*   tk  = (const int*)d_in[2];
    const float* Wq  = (const float*)d_in[3];
    const float* Wkv = (const float*)d_in[4];
    const float* Wo  = (const float*)d_in[5];
    const float* bo  = (const float*)d_in[6];
    float* out = (float*)d_out;

    char* ws = (char*)d_ws;
    _Float16* xh  = (_Float16*)(ws);                    //  8 MB [4096][1024]
    _Float16* w1t = (_Float16*)(ws + 8388608);          //  6 MB [3072][1024]
    _Float16* w2t = (_Float16*)(ws + 14680064);         //  2 MB [1024][1024]
    _Float16* qkv = (_Float16*)(ws + 16777216);         // 16 MB [4096][2048] (q|k)
    _Float16* vt  = (_Float16*)(ws + 33554432);         //  8 MB [32 bh][64 d][2048 n]
    _Float16* ao  = (_Float16*)(ws + 41943040);         //  8 MB [4096][1024]

    convx_kernel<<<2048, 256, 0, stream>>>(x, xh, 524288);
    transw_all_kernel<<<dim3(64, 16), 256, 0, stream>>>(Wq, Wkv, Wo, w1t, w2t);

    gemm_kernel<false><<<dim3(24, 32), 256, 0, stream>>>(xh, w1t, qkv, nullptr, vt,
                                                         4096, 3072, 1024, 2048);

    rope_kernel<<<4096, 256, 0, stream>>>(qkv, tq, tk);

    attn_kernel<<<512, 256, 0, stream>>>(qkv, vt, ao);

    gemm_kernel<true><<<dim3(8, 32), 256, 0, stream>>>(ao, w2t, out, bo, nullptr,
                                                       4096, 1024, 1024, 1024);
}